// Round 1
// baseline (2910.589 us; speedup 1.0000x reference)
//
#include <hip/hip_runtime.h>

// ---------------- types / constants ----------------
typedef short short8 __attribute__((ext_vector_type(8)));
typedef float f32x4 __attribute__((ext_vector_type(4)));

#define DMODEL 1024
#define HKDIM 1024
#define MDIM 4096
#define NROW 4096   // S*B = 1024*4
#define VOCAB 32000
#define NLAYER 6

__device__ __forceinline__ unsigned short f2bf(float f) {
  unsigned u = __float_as_uint(f);
  u += 0x7fffu + ((u >> 16) & 1u);
  return (unsigned short)(u >> 16);
}
__device__ __forceinline__ float bf2f(unsigned short h) {
  return __uint_as_float(((unsigned)h) << 16);
}
__device__ __forceinline__ float wave_sum(float v) {
  for (int o = 32; o; o >>= 1) v += __shfl_xor(v, o);
  return v;
}
__device__ __forceinline__ float wave_max(float v) {
  for (int o = 32; o; o >>= 1) v = fmaxf(v, __shfl_xor(v, o));
  return v;
}

// ---------------- embedding: z[s*4+b][d] = relu(wemb[x]*32 + pemb[s]) ----------------
__global__ __launch_bounds__(256) void k_embed(const int* __restrict__ x,
    const float* __restrict__ wemb, const float* __restrict__ pemb,
    float* __restrict__ z) {
  int r = blockIdx.x;           // r = s*4 + b
  int s = r >> 2;
  int tok = x[r];
  float4 a = ((const float4*)(wemb + (long)tok * DMODEL))[threadIdx.x];
  float4 p = ((const float4*)(pemb + (long)s * DMODEL))[threadIdx.x];
  float4 o;
  o.x = fmaxf(a.x * 32.0f + p.x, 0.0f);
  o.y = fmaxf(a.y * 32.0f + p.y, 0.0f);
  o.z = fmaxf(a.z * 32.0f + p.z, 0.0f);
  o.w = fmaxf(a.w * 32.0f + p.w, 0.0f);
  ((float4*)(z + (long)r * DMODEL))[threadIdx.x] = o;
}

// ---------------- permute rows: x = swapaxes(z,0,1), write f32 + bf16 ----------------
__global__ __launch_bounds__(256) void k_permute(const float* __restrict__ zin,
    float* __restrict__ xf, unsigned short* __restrict__ xb, int A0, int A1) {
  int r = blockIdx.x;                 // output row in [A1][A0] layout
  int a1 = r / A0, a0 = r - a1 * A0;  // src row = a0*A1 + a1
  float4 v = ((const float4*)(zin + (long)(a0 * A1 + a1) * DMODEL))[threadIdx.x];
  ((float4*)(xf + (long)r * DMODEL))[threadIdx.x] = v;
  ushort4 o = make_ushort4(f2bf(v.x), f2bf(v.y), f2bf(v.z), f2bf(v.w));
  ((ushort4*)(xb + (long)r * DMODEL))[threadIdx.x] = o;
}

// ---------------- f32 -> bf16 conversion (n multiple of 4) ----------------
__global__ __launch_bounds__(256) void k_cvt(const float* __restrict__ in,
    unsigned short* __restrict__ out, int n4) {
  int i = blockIdx.x * 256 + threadIdx.x;
  int stride = gridDim.x * 256;
  for (; i < n4; i += stride) {
    float4 v = ((const float4*)in)[i];
    ((ushort4*)out)[i] = make_ushort4(f2bf(v.x), f2bf(v.y), f2bf(v.z), f2bf(v.w));
  }
}

// ---------------- bf16 GEMM: C[M,N] = scale*(A[M,K] @ B[N,K]^T) + bias + res ---------
// 256 threads = 4 waves (2x2), 128x128 tile, BK=64, mfma_f32_16x16x32_bf16.
__global__ __launch_bounds__(256) void k_gemm_bt(
    const unsigned short* __restrict__ A, const unsigned short* __restrict__ B,
    float* __restrict__ Cf, unsigned short* __restrict__ Cb,
    const float* __restrict__ bias, const float* __restrict__ res,
    int M, int N, int K, long aB, long bB, long cB, float scale) {
  __shared__ unsigned short As[128][72];  // +8 pad: 144B row stride, conflict-light
  __shared__ unsigned short Bs[128][72];
  const int tid = threadIdx.x;
  const int bz = blockIdx.z;
  const unsigned short* Ab = A + bz * aB;
  const unsigned short* Bb = B + bz * bB;
  const int row0 = blockIdx.y * 128, col0 = blockIdx.x * 128;
  const int lane = tid & 63, w = tid >> 6;
  const int wm = w >> 1, wn = w & 1;
  const int fr = lane & 15, fg = lane >> 4;
  const int srow = tid >> 3, scol = (tid & 7) * 8;

  f32x4 acc[4][4];
  for (int i = 0; i < 4; ++i)
    for (int j = 0; j < 4; ++j)
      for (int q = 0; q < 4; ++q) acc[i][j][q] = 0.0f;

  for (int k0 = 0; k0 < K; k0 += 64) {
    for (int it = 0; it < 4; ++it) {
      int rr = srow + it * 32;
      *(short8*)(&As[rr][scol]) =
          *(const short8*)(Ab + (long)(row0 + rr) * K + k0 + scol);
      *(short8*)(&Bs[rr][scol]) =
          *(const short8*)(Bb + (long)(col0 + rr) * K + k0 + scol);
    }
    __syncthreads();
    for (int kk = 0; kk < 64; kk += 32) {
      short8 af[4], bf[4];
      for (int i = 0; i < 4; ++i) {
        af[i] = *(const short8*)(&As[wm * 64 + i * 16 + fr][kk + fg * 8]);
        bf[i] = *(const short8*)(&Bs[wn * 64 + i * 16 + fr][kk + fg * 8]);
      }
      for (int i = 0; i < 4; ++i)
        for (int j = 0; j < 4; ++j)
          acc[i][j] = __builtin_amdgcn_mfma_f32_16x16x32_bf16(af[i], bf[j], acc[i][j], 0, 0, 0);
    }
    __syncthreads();
  }

  for (int j = 0; j < 4; ++j) {
    int col = col0 + wn * 64 + j * 16 + fr;
    float bv = bias ? bias[col] : 0.0f;
    for (int i = 0; i < 4; ++i) {
      for (int q = 0; q < 4; ++q) {
        int row = row0 + wm * 64 + i * 16 + fg * 4 + q;
        long off = cB * bz + (long)row * N + col;
        float v = acc[i][j][q] * scale + bv;
        if (res) v += res[off];
        if (Cf) Cf[off] = v;
        if (Cb) Cb[off] = f2bf(v);
      }
    }
  }
}

// ---------------- layernorm over rows of 1024, optional add, write f32 (+bf16) -------
__global__ __launch_bounds__(256) void k_ln(const float* __restrict__ X,
    const float* __restrict__ X2, const float* __restrict__ g,
    const float* __restrict__ b, float* __restrict__ outF,
    unsigned short* __restrict__ outB) {
  __shared__ float sm[4];
  int row = blockIdx.x, t = threadIdx.x;
  float4 v = ((const float4*)(X + (long)row * DMODEL))[t];
  if (X2) {
    float4 u = ((const float4*)(X2 + (long)row * DMODEL))[t];
    v.x += u.x; v.y += u.y; v.z += u.z; v.w += u.w;
  }
  float s = wave_sum(v.x + v.y + v.z + v.w);
  if ((t & 63) == 0) sm[t >> 6] = s;
  __syncthreads();
  float mean = (sm[0] + sm[1] + sm[2] + sm[3]) * (1.0f / DMODEL);
  __syncthreads();
  float4 c;
  c.x = v.x - mean; c.y = v.y - mean; c.z = v.z - mean; c.w = v.w - mean;
  float ss = wave_sum(c.x * c.x + c.y * c.y + c.z * c.z + c.w * c.w);
  if ((t & 63) == 0) sm[t >> 6] = ss;
  __syncthreads();
  float var = (sm[0] + sm[1] + sm[2] + sm[3]) * (1.0f / DMODEL);
  float rs = rsqrtf(var + 1e-5f);
  float4 gv = ((const float4*)g)[t], bv = ((const float4*)b)[t];
  float4 o;
  o.x = c.x * rs * gv.x + bv.x;
  o.y = c.y * rs * gv.y + bv.y;
  o.z = c.z * rs * gv.z + bv.z;
  o.w = c.w * rs * gv.w + bv.w;
  if (outF) ((float4*)(outF + (long)row * DMODEL))[t] = o;
  if (outB)
    ((ushort4*)(outB + (long)row * DMODEL))[t] =
        make_ushort4(f2bf(o.x), f2bf(o.y), f2bf(o.z), f2bf(o.w));
}

// ---------------- softmax over rows of 1024 (f32 in, bf16 out) ----------------
__global__ __launch_bounds__(256) void k_softmax(const float* __restrict__ S,
    unsigned short* __restrict__ A) {
  __shared__ float sm[4];
  int row = blockIdx.x, t = threadIdx.x;
  float4 v = ((const float4*)(S + (long)row * 1024))[t];
  float m = wave_max(fmaxf(fmaxf(v.x, v.y), fmaxf(v.z, v.w)));
  if ((t & 63) == 0) sm[t >> 6] = m;
  __syncthreads();
  m = fmaxf(fmaxf(sm[0], sm[1]), fmaxf(sm[2], sm[3]));
  __syncthreads();
  float4 e;
  e.x = __expf(v.x - m); e.y = __expf(v.y - m);
  e.z = __expf(v.z - m); e.w = __expf(v.w - m);
  float s = wave_sum(e.x + e.y + e.z + e.w);
  if ((t & 63) == 0) sm[t >> 6] = s;
  __syncthreads();
  float inv = 1.0f / (sm[0] + sm[1] + sm[2] + sm[3]);
  ((ushort4*)(A + (long)row * 1024))[t] =
      make_ushort4(f2bf(e.x * inv), f2bf(e.y * inv), f2bf(e.z * inv), f2bf(e.w * inv));
}

// ---------------- odd layers: attention with seq length 4 (fused) ----------------
__global__ __launch_bounds__(256) void k_attn4(const unsigned short* __restrict__ Q,
    const unsigned short* __restrict__ K, const unsigned short* __restrict__ V,
    unsigned short* __restrict__ C) {
  int bp = blockIdx.x;                 // 0..1023 "batch"
  int w = threadIdx.x >> 6, lane = threadIdx.x & 63;  // wave = query row
  const unsigned short* q = Q + (long)(bp * 4 + w) * 1024;
  float s[4];
  for (int j = 0; j < 4; ++j) {
    const unsigned short* kj = K + (long)(bp * 4 + j) * 1024;
    float a = 0.0f;
    for (int e = lane; e < 1024; e += 64) a += bf2f(q[e]) * bf2f(kj[e]);
    s[j] = wave_sum(a) * (1.0f / 32.0f);
  }
  float m = fmaxf(fmaxf(s[0], s[1]), fmaxf(s[2], s[3]));
  float e0 = __expf(s[0] - m), e1 = __expf(s[1] - m);
  float e2 = __expf(s[2] - m), e3 = __expf(s[3] - m);
  float inv = 1.0f / (e0 + e1 + e2 + e3);
  float a0 = e0 * inv, a1 = e1 * inv, a2 = e2 * inv, a3 = e3 * inv;
  unsigned short* c = C + (long)(bp * 4 + w) * 1024;
  const unsigned short* v0 = V + (long)(bp * 4 + 0) * 1024;
  const unsigned short* v1 = V + (long)(bp * 4 + 1) * 1024;
  const unsigned short* v2 = V + (long)(bp * 4 + 2) * 1024;
  const unsigned short* v3 = V + (long)(bp * 4 + 3) * 1024;
  for (int e = lane; e < 1024; e += 64) {
    float v = a0 * bf2f(v0[e]) + a1 * bf2f(v1[e]) + a2 * bf2f(v2[e]) + a3 * bf2f(v3[e]);
    c[e] = f2bf(v);
  }
}

// ---------------- bf16 batched transpose [rows,cols] -> [cols,rows] ----------------
__global__ __launch_bounds__(256) void k_transpose(const unsigned short* __restrict__ in,
    unsigned short* __restrict__ out, int rows, int cols) {
  __shared__ unsigned short tile[32][33];
  long base = (long)blockIdx.z * rows * cols;
  int r0 = blockIdx.y * 32, c0 = blockIdx.x * 32;
  int tx = threadIdx.x, ty = threadIdx.y;
  for (int i = ty; i < 32; i += 8)
    tile[i][tx] = in[base + (long)(r0 + i) * cols + c0 + tx];
  __syncthreads();
  for (int i = ty; i < 32; i += 8)
    out[base + (long)(c0 + i) * rows + r0 + tx] = tile[tx][i];
}

// ---------------- decoder log-softmax: row stats then subtract ----------------
__global__ __launch_bounds__(256) void k_lse(const float* __restrict__ L,
    float* __restrict__ st) {
  __shared__ float sm[4];
  int row = blockIdx.x, t = threadIdx.x;
  const float* x = L + (long)row * VOCAB;
  float m = -1e30f;
  for (int c = t; c < VOCAB; c += 256) m = fmaxf(m, x[c]);
  m = wave_max(m);
  if ((t & 63) == 0) sm[t >> 6] = m;
  __syncthreads();
  m = fmaxf(fmaxf(sm[0], sm[1]), fmaxf(sm[2], sm[3]));
  __syncthreads();
  float s = 0.0f;
  for (int c = t; c < VOCAB; c += 256) s += __expf(x[c] - m);
  s = wave_sum(s);
  if ((t & 63) == 0) sm[t >> 6] = s;
  __syncthreads();
  if (t == 0) st[row] = m + __logf(sm[0] + sm[1] + sm[2] + sm[3]);
}

__global__ __launch_bounds__(256) void k_lsub(float* __restrict__ L,
    const float* __restrict__ st) {
  int row = blockIdx.y;
  float l = st[row];
  int c = (blockIdx.x * 256 + threadIdx.x) * 4;
  if (c + 3 < VOCAB) {
    float4* p = (float4*)(L + (long)row * VOCAB + c);
    float4 v = *p;
    v.x -= l; v.y -= l; v.z -= l; v.w -= l;
    *p = v;
  }
}

__global__ __launch_bounds__(256) void k_addbias(const float* __restrict__ a,
    const float* __restrict__ b, float* __restrict__ o, int n) {
  int i = blockIdx.x * 256 + threadIdx.x;
  if (i < n) o[i] = a[i] + b[i];
}

// ---------------- host ----------------
extern "C" void kernel_launch(void* const* d_in, const int* in_sizes, int n_in,
                              void* d_out, int out_size, void* d_ws, size_t ws_size,
                              hipStream_t stream) {
  const int* x = (const int*)d_in[0];
  const float* wemb = (const float*)d_in[1];
  const float* pemb = (const float*)d_in[2];
  const float* wq = (const float*)d_in[3];
  const float* wk = (const float*)d_in[4];
  const float* wv = (const float*)d_in[5];
  const float* wc = (const float*)d_in[6];
  const float* ln1g = (const float*)d_in[7];
  const float* ln1b = (const float*)d_in[8];
  const float* w1 = (const float*)d_in[9];
  const float* b1 = (const float*)d_in[10];
  const float* w2 = (const float*)d_in[11];
  const float* b2 = (const float*)d_in[12];
  const float* ln2g = (const float*)d_in[13];
  const float* ln2b = (const float*)d_in[14];
  const float* decw = (const float*)d_in[15];
  const float* decb = (const float*)d_in[16];
  const float* obias = (const float*)d_in[17];
  float* out = (float*)d_out;

  char* ws = (char*)d_ws;
  size_t off = 0;
  auto alloc = [&](size_t bytes) -> char* {
    char* p = ws + off;
    off += (bytes + 255) & ~(size_t)255;
    return p;
  };
  float* z = (float*)alloc((size_t)NROW * DMODEL * 4);
  float* xf = (float*)alloc((size_t)NROW * DMODEL * 4);
  unsigned short* xb = (unsigned short*)alloc((size_t)NROW * DMODEL * 2);
  unsigned short* qb = (unsigned short*)alloc((size_t)NROW * HKDIM * 2);
  unsigned short* kb = (unsigned short*)alloc((size_t)NROW * HKDIM * 2);
  unsigned short* vb = (unsigned short*)alloc((size_t)NROW * HKDIM * 2);
  unsigned short* vt = (unsigned short*)alloc((size_t)NROW * HKDIM * 2);
  unsigned short* wbuf = (unsigned short*)alloc((size_t)MDIM * DMODEL * 2);
  float* tmp16 = (float*)alloc((size_t)NROW * 1024 * 4);  // scores / att / f2 (disjoint lifetimes)
  unsigned short* am = (unsigned short*)alloc((size_t)NROW * 1024 * 2);
  unsigned short* ctx = (unsigned short*)alloc((size_t)NROW * HKDIM * 2);
  float* h = (float*)alloc((size_t)NROW * DMODEL * 4);
  unsigned short* hb = (unsigned short*)alloc((size_t)NROW * DMODEL * 2);
  unsigned short* f = (unsigned short*)alloc((size_t)NROW * MDIM * 2);
  unsigned short* dwb = (unsigned short*)alloc((size_t)VOCAB * DMODEL * 2);
  unsigned short* zb = (unsigned short*)alloc((size_t)NROW * DMODEL * 2);
  float* biasD = (float*)alloc((size_t)VOCAB * 4);
  float* stats = (float*)alloc((size_t)NROW * 4);
  (void)ws_size; (void)in_sizes; (void)n_in; (void)out_size;

  auto gemm = [&](const unsigned short* A, const unsigned short* B, float* Cf,
                  unsigned short* Cb, const float* bias, const float* res, int M,
                  int N, int K, int batch, long aB, long bB, long cB, float scale) {
    dim3 g(N / 128, M / 128, batch);
    k_gemm_bt<<<g, dim3(256), 0, stream>>>(A, B, Cf, Cb, bias, res, M, N, K, aB, bB, cB, scale);
  };
  auto cvt = [&](const float* in, unsigned short* o, long n) {
    int n4 = (int)(n / 4);
    int grid = (n4 + 255) / 256;
    if (grid > 2048) grid = 2048;
    k_cvt<<<dim3(grid), dim3(256), 0, stream>>>(in, o, n4);
  };

  k_embed<<<NROW, 256, 0, stream>>>(x, wemb, pemb, z);

  for (int i = 0; i < NLAYER; ++i) {
    int A0 = (i % 2 == 0) ? 1024 : 4;  // input layout dim0; Sp (post-swap seq) = A0
    int A1 = 4096 / A0;
    k_permute<<<NROW, 256, 0, stream>>>(z, xf, xb, A0, A1);

    cvt(wq + (long)i * HKDIM * DMODEL, wbuf, (long)HKDIM * DMODEL);
    gemm(xb, wbuf, nullptr, qb, nullptr, nullptr, NROW, HKDIM, DMODEL, 1, 0, 0, 0, 1.0f);
    cvt(wk + (long)i * HKDIM * DMODEL, wbuf, (long)HKDIM * DMODEL);
    gemm(xb, wbuf, nullptr, kb, nullptr, nullptr, NROW, HKDIM, DMODEL, 1, 0, 0, 0, 1.0f);
    cvt(wv + (long)i * HKDIM * DMODEL, wbuf, (long)HKDIM * DMODEL);
    gemm(xb, wbuf, nullptr, vb, nullptr, nullptr, NROW, HKDIM, DMODEL, 1, 0, 0, 0, 1.0f);

    if (A0 == 1024) {  // even: full attention over S=1024, 4 batches
      gemm(qb, kb, tmp16, nullptr, nullptr, nullptr, 1024, 1024, 1024, 4,
           1 << 20, 1 << 20, 1 << 20, 1.0f / 32.0f);
      k_softmax<<<NROW, 256, 0, stream>>>(tmp16, am);
      k_transpose<<<dim3(32, 32, 4), dim3(32, 8), 0, stream>>>(vb, vt, 1024, 1024);
      gemm(am, vt, nullptr, ctx, nullptr, nullptr, 1024, 1024, 1024, 4,
           1 << 20, 1 << 20, 1 << 20, 1.0f);
    } else {  // odd: seq length 4, 1024 batches — fused tiny attention
      k_attn4<<<1024, 256, 0, stream>>>(qb, kb, vb, ctx);
    }

    cvt(wc + (long)i * DMODEL * HKDIM, wbuf, (long)DMODEL * HKDIM);
    gemm(ctx, wbuf, tmp16, nullptr, nullptr, xf, NROW, DMODEL, HKDIM, 1, 0, 0, 0, 1.0f);
    k_ln<<<NROW, 256, 0, stream>>>(tmp16, nullptr, ln1g + (long)i * DMODEL,
                                   ln1b + (long)i * DMODEL, h, hb);
    cvt(w1 + (long)i * MDIM * DMODEL, wbuf, (long)MDIM * DMODEL);
    gemm(hb, wbuf, nullptr, f, b1 + (long)i * MDIM, nullptr, NROW, MDIM, DMODEL, 1,
         0, 0, 0, 1.0f);
    cvt(w2 + (long)i * DMODEL * MDIM, wbuf, (long)DMODEL * MDIM);
    gemm(f, wbuf, tmp16, nullptr, b2 + (long)i * DMODEL, nullptr, NROW, DMODEL, MDIM,
         1, 0, 0, 0, 1.0f);
    k_ln<<<NROW, 256, 0, stream>>>(tmp16, h, ln2g + (long)i * DMODEL,
                                   ln2b + (long)i * DMODEL, z, nullptr);
  }

  // decoder
  cvt(z, zb, (long)NROW * DMODEL);
  cvt(decw, dwb, (long)VOCAB * DMODEL);
  k_addbias<<<(VOCAB + 255) / 256, 256, 0, stream>>>(decb, obias, biasD, VOCAB);
  gemm(zb, dwb, out, nullptr, biasD, nullptr, NROW, VOCAB, DMODEL, 1, 0, 0, 0, 1.0f);
  k_lse<<<NROW, 256, 0, stream>>>(out, stats);
  k_lsub<<<dim3(32, NROW), 256, 0, stream>>>(out, stats);
}

// Round 2
// 2834.984 us; speedup vs baseline: 1.0267x; 1.0267x over previous
//
#include <hip/hip_runtime.h>

// ---------------- types / constants ----------------
typedef short short8 __attribute__((ext_vector_type(8)));
typedef float f32x4 __attribute__((ext_vector_type(4)));

#define DMODEL 1024
#define HKDIM 1024
#define MDIM 4096
#define NROW 4096   // S*B = 1024*4
#define VOCAB 32000
#define NLAYER 6

#define GLOAD_LDS16(g, l)                                                      \
  __builtin_amdgcn_global_load_lds(                                            \
      (const __attribute__((address_space(1))) void*)(g),                      \
      (__attribute__((address_space(3))) void*)(l), 16, 0, 0)

__device__ __forceinline__ unsigned short f2bf(float f) {
  unsigned u = __float_as_uint(f);
  u += 0x7fffu + ((u >> 16) & 1u);
  return (unsigned short)(u >> 16);
}
__device__ __forceinline__ float bf2f(unsigned short h) {
  return __uint_as_float(((unsigned)h) << 16);
}
__device__ __forceinline__ float wave_sum(float v) {
  for (int o = 32; o; o >>= 1) v += __shfl_xor(v, o);
  return v;
}
__device__ __forceinline__ float wave_max(float v) {
  for (int o = 32; o; o >>= 1) v = fmaxf(v, __shfl_xor(v, o));
  return v;
}

// ---------------- embedding: z[s*4+b][d] = relu(wemb[x]*32 + pemb[s]) ----------------
__global__ __launch_bounds__(256) void k_embed(const int* __restrict__ x,
    const float* __restrict__ wemb, const float* __restrict__ pemb,
    float* __restrict__ z) {
  int r = blockIdx.x;           // r = s*4 + b
  int s = r >> 2;
  int tok = x[r];
  float4 a = ((const float4*)(wemb + (long)tok * DMODEL))[threadIdx.x];
  float4 p = ((const float4*)(pemb + (long)s * DMODEL))[threadIdx.x];
  float4 o;
  o.x = fmaxf(a.x * 32.0f + p.x, 0.0f);
  o.y = fmaxf(a.y * 32.0f + p.y, 0.0f);
  o.z = fmaxf(a.z * 32.0f + p.z, 0.0f);
  o.w = fmaxf(a.w * 32.0f + p.w, 0.0f);
  ((float4*)(z + (long)r * DMODEL))[threadIdx.x] = o;
}

// ---------------- permute rows: x = swapaxes(z,0,1), write f32 + bf16 ----------------
__global__ __launch_bounds__(256) void k_permute(const float* __restrict__ zin,
    float* __restrict__ xf, unsigned short* __restrict__ xb, int A0, int A1) {
  int r = blockIdx.x;                 // output row in [A1][A0] layout
  int a1 = r / A0, a0 = r - a1 * A0;  // src row = a0*A1 + a1
  float4 v = ((const float4*)(zin + (long)(a0 * A1 + a1) * DMODEL))[threadIdx.x];
  ((float4*)(xf + (long)r * DMODEL))[threadIdx.x] = v;
  ushort4 o = make_ushort4(f2bf(v.x), f2bf(v.y), f2bf(v.z), f2bf(v.w));
  ((ushort4*)(xb + (long)r * DMODEL))[threadIdx.x] = o;
}

// ---------------- f32 -> bf16 conversion (n multiple of 4) ----------------
__global__ __launch_bounds__(256) void k_cvt(const float* __restrict__ in,
    unsigned short* __restrict__ out, int n4) {
  int i = blockIdx.x * 256 + threadIdx.x;
  int stride = gridDim.x * 256;
  for (; i < n4; i += stride) {
    float4 v = ((const float4*)in)[i];
    ((ushort4*)out)[i] = make_ushort4(f2bf(v.x), f2bf(v.y), f2bf(v.z), f2bf(v.w));
  }
}

// ---------------- bf16 GEMM: C[M,N] = scale*(A[M,K] @ B[N,K]^T) + bias + res ---------
// 256 threads = 4 waves (2x2), 128x128 tile, BK=64, mfma_f32_16x16x32_bf16.
// m97 structure: global_load_lds width-16 staging into linear LDS, 2 barriers/K-step.
// XCD-aware bijective block swizzle (m204), y-fastest tile order within chunks.
__global__ __launch_bounds__(256) void k_gemm_bt(
    const unsigned short* __restrict__ A, const unsigned short* __restrict__ B,
    float* __restrict__ Cf, unsigned short* __restrict__ Cb,
    const float* __restrict__ bias, const float* __restrict__ res,
    int M, int N, int K, int lda, int ldb, int ldc,
    long aB, long bB, long cB, float scale) {
  __shared__ unsigned short As[128 * 64];
  __shared__ unsigned short Bs[128 * 64];
  const int tid = threadIdx.x;
  const int gx = gridDim.x, gy = gridDim.y;

  // --- bijective XCD swizzle over the flat dispatch id ---
  int nwg = gx * gy * gridDim.z;
  int flat = blockIdx.x + gx * (blockIdx.y + gy * blockIdx.z);
  int q8 = nwg >> 3, r8 = nwg & 7;
  int xcd = flat & 7, inner = flat >> 3;
  int wg = (xcd < r8 ? xcd * (q8 + 1) : r8 * (q8 + 1) + (xcd - r8) * q8) + inner;
  // y-fastest decomposition: co-XCD blocks share B-tiles (tx) consecutively
  int ty = wg % gy;
  int rest = wg / gy;
  int tx = rest % gx;
  int tz = rest / gx;

  const unsigned short* Ab = A + (long)tz * aB;
  const unsigned short* Bb = B + (long)tz * bB;
  const int row0 = ty * 128, col0 = tx * 128;
  const int lane = tid & 63, w = tid >> 6;
  const int wm = w >> 1, wn = w & 1;
  const int fr = lane & 15, fg = lane >> 4;
  const int lrow = lane >> 3, lcol = (lane & 7) * 8;

  // per-wave staging: wave w stages rows [w*32, w*32+32) of both tiles
  const unsigned short* aSrc = Ab + (long)(row0 + w * 32 + lrow) * lda + lcol;
  const unsigned short* bSrc = Bb + (long)(col0 + w * 32 + lrow) * ldb + lcol;
  unsigned short* aDst = As + w * 32 * 64;  // wave-uniform LDS base
  unsigned short* bDst = Bs + w * 32 * 64;

  f32x4 acc[4][4];
  for (int i = 0; i < 4; ++i)
    for (int j = 0; j < 4; ++j)
      for (int qq = 0; qq < 4; ++qq) acc[i][j][qq] = 0.0f;

  for (int k0 = 0; k0 < K; k0 += 64) {
#pragma unroll
    for (int i = 0; i < 4; ++i) {
      GLOAD_LDS16(aSrc + (long)i * 8 * lda + k0, aDst + i * 512);
      GLOAD_LDS16(bSrc + (long)i * 8 * ldb + k0, bDst + i * 512);
    }
    __syncthreads();  // drains vmcnt (incl. global_load_lds) then barrier
#pragma unroll
    for (int kk = 0; kk < 64; kk += 32) {
      short8 af[4], bfr[4];
#pragma unroll
      for (int i = 0; i < 4; ++i) {
        af[i] = *(const short8*)(As + (wm * 64 + i * 16 + fr) * 64 + kk + fg * 8);
        bfr[i] = *(const short8*)(Bs + (wn * 64 + i * 16 + fr) * 64 + kk + fg * 8);
      }
#pragma unroll
      for (int i = 0; i < 4; ++i)
#pragma unroll
        for (int j = 0; j < 4; ++j)
          acc[i][j] = __builtin_amdgcn_mfma_f32_16x16x32_bf16(af[i], bfr[j], acc[i][j], 0, 0, 0);
    }
    __syncthreads();
  }

  for (int j = 0; j < 4; ++j) {
    int col = col0 + wn * 64 + j * 16 + fr;
    float bv = bias ? bias[col] : 0.0f;
    for (int i = 0; i < 4; ++i) {
      for (int qq = 0; qq < 4; ++qq) {
        int row = row0 + wm * 64 + i * 16 + fg * 4 + qq;
        long off = cB * tz + (long)row * ldc + col;
        float v = acc[i][j][qq] * scale + bv;
        if (res) v += res[off];
        if (Cf) Cf[off] = v;
        if (Cb) Cb[off] = f2bf(v);
      }
    }
  }
}

// ---------------- layernorm over rows of 1024, optional add, write f32 (+bf16) -------
__global__ __launch_bounds__(256) void k_ln(const float* __restrict__ X,
    const float* __restrict__ X2, const float* __restrict__ g,
    const float* __restrict__ b, float* __restrict__ outF,
    unsigned short* __restrict__ outB) {
  __shared__ float sm[4];
  int row = blockIdx.x, t = threadIdx.x;
  float4 v = ((const float4*)(X + (long)row * DMODEL))[t];
  if (X2) {
    float4 u = ((const float4*)(X2 + (long)row * DMODEL))[t];
    v.x += u.x; v.y += u.y; v.z += u.z; v.w += u.w;
  }
  float s = wave_sum(v.x + v.y + v.z + v.w);
  if ((t & 63) == 0) sm[t >> 6] = s;
  __syncthreads();
  float mean = (sm[0] + sm[1] + sm[2] + sm[3]) * (1.0f / DMODEL);
  __syncthreads();
  float4 c;
  c.x = v.x - mean; c.y = v.y - mean; c.z = v.z - mean; c.w = v.w - mean;
  float ss = wave_sum(c.x * c.x + c.y * c.y + c.z * c.z + c.w * c.w);
  if ((t & 63) == 0) sm[t >> 6] = ss;
  __syncthreads();
  float var = (sm[0] + sm[1] + sm[2] + sm[3]) * (1.0f / DMODEL);
  float rs = rsqrtf(var + 1e-5f);
  float4 gv = ((const float4*)g)[t], bv = ((const float4*)b)[t];
  float4 o;
  o.x = c.x * rs * gv.x + bv.x;
  o.y = c.y * rs * gv.y + bv.y;
  o.z = c.z * rs * gv.z + bv.z;
  o.w = c.w * rs * gv.w + bv.w;
  if (outF) ((float4*)(outF + (long)row * DMODEL))[t] = o;
  if (outB)
    ((ushort4*)(outB + (long)row * DMODEL))[t] =
        make_ushort4(f2bf(o.x), f2bf(o.y), f2bf(o.z), f2bf(o.w));
}

// ---------------- softmax over rows of 1024 (f32 in, bf16 out) ----------------
__global__ __launch_bounds__(256) void k_softmax(const float* __restrict__ S,
    unsigned short* __restrict__ A) {
  __shared__ float sm[4];
  int row = blockIdx.x, t = threadIdx.x;
  float4 v = ((const float4*)(S + (long)row * 1024))[t];
  float m = wave_max(fmaxf(fmaxf(v.x, v.y), fmaxf(v.z, v.w)));
  if ((t & 63) == 0) sm[t >> 6] = m;
  __syncthreads();
  m = fmaxf(fmaxf(sm[0], sm[1]), fmaxf(sm[2], sm[3]));
  __syncthreads();
  float4 e;
  e.x = __expf(v.x - m); e.y = __expf(v.y - m);
  e.z = __expf(v.z - m); e.w = __expf(v.w - m);
  float s = wave_sum(e.x + e.y + e.z + e.w);
  if ((t & 63) == 0) sm[t >> 6] = s;
  __syncthreads();
  float inv = 1.0f / (sm[0] + sm[1] + sm[2] + sm[3]);
  ((ushort4*)(A + (long)row * 1024))[t] =
      make_ushort4(f2bf(e.x * inv), f2bf(e.y * inv), f2bf(e.z * inv), f2bf(e.w * inv));
}

// ---------------- odd layers: attention with seq length 4 (fused) ----------------
// QKV packed layout: row stride 3072, q/k/v at col offsets 0/1024/2048.
__global__ __launch_bounds__(256) void k_attn4(const unsigned short* __restrict__ QKV,
    unsigned short* __restrict__ C) {
  int bp = blockIdx.x;                 // 0..1023 "batch"
  int w = threadIdx.x >> 6, lane = threadIdx.x & 63;  // wave = query row
  const unsigned short* q = QKV + (long)(bp * 4 + w) * 3072;
  float s[4];
  for (int j = 0; j < 4; ++j) {
    const unsigned short* kj = QKV + (long)(bp * 4 + j) * 3072 + 1024;
    float a = 0.0f;
    for (int e = lane; e < 1024; e += 64) a += bf2f(q[e]) * bf2f(kj[e]);
    s[j] = wave_sum(a) * (1.0f / 32.0f);
  }
  float m = fmaxf(fmaxf(s[0], s[1]), fmaxf(s[2], s[3]));
  float e0 = __expf(s[0] - m), e1 = __expf(s[1] - m);
  float e2 = __expf(s[2] - m), e3 = __expf(s[3] - m);
  float inv = 1.0f / (e0 + e1 + e2 + e3);
  float a0 = e0 * inv, a1 = e1 * inv, a2 = e2 * inv, a3 = e3 * inv;
  unsigned short* c = C + (long)(bp * 4 + w) * 1024;
  const unsigned short* v0 = QKV + (long)(bp * 4 + 0) * 3072 + 2048;
  const unsigned short* v1 = QKV + (long)(bp * 4 + 1) * 3072 + 2048;
  const unsigned short* v2 = QKV + (long)(bp * 4 + 2) * 3072 + 2048;
  const unsigned short* v3 = QKV + (long)(bp * 4 + 3) * 3072 + 2048;
  for (int e = lane; e < 1024; e += 64) {
    float v = a0 * bf2f(v0[e]) + a1 * bf2f(v1[e]) + a2 * bf2f(v2[e]) + a3 * bf2f(v3[e]);
    c[e] = f2bf(v);
  }
}

// ---------------- bf16 batched transpose with strides ----------------
__global__ __launch_bounds__(256) void k_transpose(const unsigned short* __restrict__ in,
    unsigned short* __restrict__ out, int rows, int cols, int ld_in, int ld_out,
    long inB, long outB) {
  __shared__ unsigned short tile[32][33];
  long ibase = (long)blockIdx.z * inB;
  long obase = (long)blockIdx.z * outB;
  int r0 = blockIdx.y * 32, c0 = blockIdx.x * 32;
  int tx = threadIdx.x, ty = threadIdx.y;
  for (int i = ty; i < 32; i += 8)
    tile[i][tx] = in[ibase + (long)(r0 + i) * ld_in + c0 + tx];
  __syncthreads();
  for (int i = ty; i < 32; i += 8)
    out[obase + (long)(c0 + i) * ld_out + r0 + tx] = tile[tx][i];
}

// ---------------- fused log-softmax over rows of 32000 (in-place, f32) --------------
// 320 threads, 25 float4 per thread held in registers: single read + single write.
__global__ __launch_bounds__(320) void k_logsoftmax(float* __restrict__ L) {
  __shared__ float sm[5];
  int row = blockIdx.x, t = threadIdx.x;
  float* x = L + (long)row * VOCAB;
  float4 v[25];
  float m = -1e30f;
#pragma unroll
  for (int i = 0; i < 25; ++i) {
    v[i] = ((const float4*)x)[t + i * 320];
    m = fmaxf(m, fmaxf(fmaxf(v[i].x, v[i].y), fmaxf(v[i].z, v[i].w)));
  }
  m = wave_max(m);
  if ((t & 63) == 0) sm[t >> 6] = m;
  __syncthreads();
  m = fmaxf(fmaxf(fmaxf(sm[0], sm[1]), fmaxf(sm[2], sm[3])), sm[4]);
  __syncthreads();
  float s = 0.0f;
#pragma unroll
  for (int i = 0; i < 25; ++i)
    s += __expf(v[i].x - m) + __expf(v[i].y - m) + __expf(v[i].z - m) + __expf(v[i].w - m);
  s = wave_sum(s);
  if ((t & 63) == 0) sm[t >> 6] = s;
  __syncthreads();
  float l = m + __logf(sm[0] + sm[1] + sm[2] + sm[3] + sm[4]);
#pragma unroll
  for (int i = 0; i < 25; ++i) {
    float4 o = v[i];
    o.x -= l; o.y -= l; o.z -= l; o.w -= l;
    ((float4*)x)[t + i * 320] = o;
  }
}

__global__ __launch_bounds__(256) void k_addbias(const float* __restrict__ a,
    const float* __restrict__ b, float* __restrict__ o, int n) {
  int i = blockIdx.x * 256 + threadIdx.x;
  if (i < n) o[i] = a[i] + b[i];
}

// ---------------- host ----------------
extern "C" void kernel_launch(void* const* d_in, const int* in_sizes, int n_in,
                              void* d_out, int out_size, void* d_ws, size_t ws_size,
                              hipStream_t stream) {
  const int* x = (const int*)d_in[0];
  const float* wemb = (const float*)d_in[1];
  const float* pemb = (const float*)d_in[2];
  const float* wq = (const float*)d_in[3];
  const float* wk = (const float*)d_in[4];
  const float* wv = (const float*)d_in[5];
  const float* wc = (const float*)d_in[6];
  const float* ln1g = (const float*)d_in[7];
  const float* ln1b = (const float*)d_in[8];
  const float* w1 = (const float*)d_in[9];
  const float* b1 = (const float*)d_in[10];
  const float* w2 = (const float*)d_in[11];
  const float* b2 = (const float*)d_in[12];
  const float* ln2g = (const float*)d_in[13];
  const float* ln2b = (const float*)d_in[14];
  const float* decw = (const float*)d_in[15];
  const float* decb = (const float*)d_in[16];
  const float* obias = (const float*)d_in[17];
  float* out = (float*)d_out;

  char* ws = (char*)d_ws;
  size_t off = 0;
  auto alloc = [&](size_t bytes) -> char* {
    char* p = ws + off;
    off += (bytes + 255) & ~(size_t)255;
    return p;
  };
  float* z = (float*)alloc((size_t)NROW * DMODEL * 4);
  float* xf = (float*)alloc((size_t)NROW * DMODEL * 4);
  unsigned short* xb = (unsigned short*)alloc((size_t)NROW * DMODEL * 2);
  unsigned short* qkv = (unsigned short*)alloc((size_t)NROW * 3072 * 2);
  unsigned short* vt = (unsigned short*)alloc((size_t)NROW * HKDIM * 2);
  unsigned short* wbuf = (unsigned short*)alloc((size_t)MDIM * DMODEL * 2);
  float* tmp16 = (float*)alloc((size_t)NROW * 1024 * 4);  // scores / att / f2 (disjoint lifetimes)
  unsigned short* am = (unsigned short*)alloc((size_t)NROW * 1024 * 2);
  unsigned short* ctx = (unsigned short*)alloc((size_t)NROW * HKDIM * 2);
  float* h = (float*)alloc((size_t)NROW * DMODEL * 4);
  unsigned short* hb = (unsigned short*)alloc((size_t)NROW * DMODEL * 2);
  unsigned short* f = (unsigned short*)alloc((size_t)NROW * MDIM * 2);
  unsigned short* dwb = (unsigned short*)alloc((size_t)VOCAB * DMODEL * 2);
  unsigned short* zb = (unsigned short*)alloc((size_t)NROW * DMODEL * 2);
  float* biasD = (float*)alloc((size_t)VOCAB * 4);
  (void)ws_size; (void)in_sizes; (void)n_in; (void)out_size;

  auto gemm = [&](const unsigned short* A, const unsigned short* B, float* Cf,
                  unsigned short* Cb, const float* bias, const float* res, int M,
                  int N, int K, int lda, int ldb, int ldc, int batch, long aB,
                  long bB, long cB, float scale) {
    dim3 g(N / 128, M / 128, batch);
    k_gemm_bt<<<g, dim3(256), 0, stream>>>(A, B, Cf, Cb, bias, res, M, N, K,
                                           lda, ldb, ldc, aB, bB, cB, scale);
  };
  auto cvt = [&](const float* in, unsigned short* o, long n) {
    int n4 = (int)(n / 4);
    int grid = (n4 + 255) / 256;
    if (grid > 2048) grid = 2048;
    k_cvt<<<dim3(grid), dim3(256), 0, stream>>>(in, o, n4);
  };

  k_embed<<<NROW, 256, 0, stream>>>(x, wemb, pemb, z);

  for (int i = 0; i < NLAYER; ++i) {
    int A0 = (i % 2 == 0) ? 1024 : 4;  // input layout dim0; Sp (post-swap seq) = A0
    int A1 = 4096 / A0;
    k_permute<<<NROW, 256, 0, stream>>>(z, xf, xb, A0, A1);

    // merged QKV: weights stacked [3072,1024] in wbuf, one GEMM N=3072
    cvt(wq + (long)i * HKDIM * DMODEL, wbuf, (long)HKDIM * DMODEL);
    cvt(wk + (long)i * HKDIM * DMODEL, wbuf + (size_t)1024 * DMODEL, (long)HKDIM * DMODEL);
    cvt(wv + (long)i * HKDIM * DMODEL, wbuf + (size_t)2048 * DMODEL, (long)HKDIM * DMODEL);
    gemm(xb, wbuf, nullptr, qkv, nullptr, nullptr, NROW, 3072, DMODEL,
         DMODEL, DMODEL, 3072, 1, 0, 0, 0, 1.0f);

    if (A0 == 1024) {  // even: full attention over S=1024, 4 batches
      gemm(qkv, qkv + 1024, tmp16, nullptr, nullptr, nullptr, 1024, 1024, 1024,
           3072, 3072, 1024, 4, (long)1024 * 3072, (long)1024 * 3072, 1 << 20,
           1.0f / 32.0f);
      k_softmax<<<NROW, 256, 0, stream>>>(tmp16, am);
      k_transpose<<<dim3(32, 32, 4), dim3(32, 8), 0, stream>>>(
          qkv + 2048, vt, 1024, 1024, 3072, 1024, (long)1024 * 3072, 1 << 20);
      gemm(am, vt, nullptr, ctx, nullptr, nullptr, 1024, 1024, 1024,
           1024, 1024, 1024, 4, 1 << 20, 1 << 20, 1 << 20, 1.0f);
    } else {  // odd: seq length 4, 1024 batches — fused tiny attention
      k_attn4<<<1024, 256, 0, stream>>>(qkv, ctx);
    }

    cvt(wc + (long)i * DMODEL * HKDIM, wbuf, (long)DMODEL * HKDIM);
    gemm(ctx, wbuf, tmp16, nullptr, nullptr, xf, NROW, DMODEL, HKDIM,
         HKDIM, HKDIM, DMODEL, 1, 0, 0, 0, 1.0f);
    k_ln<<<NROW, 256, 0, stream>>>(tmp16, nullptr, ln1g + (long)i * DMODEL,
                                   ln1b + (long)i * DMODEL, h, hb);
    cvt(w1 + (long)i * MDIM * DMODEL, wbuf, (long)MDIM * DMODEL);
    gemm(hb, wbuf, nullptr, f, b1 + (long)i * MDIM, nullptr, NROW, MDIM, DMODEL,
         DMODEL, DMODEL, MDIM, 1, 0, 0, 0, 1.0f);
    cvt(w2 + (long)i * DMODEL * MDIM, wbuf, (long)DMODEL * MDIM);
    gemm(f, wbuf, tmp16, nullptr, b2 + (long)i * DMODEL, nullptr, NROW, DMODEL, MDIM,
         MDIM, MDIM, DMODEL, 1, 0, 0, 0, 1.0f);
    k_ln<<<NROW, 256, 0, stream>>>(tmp16, h, ln2g + (long)i * DMODEL,
                                   ln2b + (long)i * DMODEL, z, nullptr);
  }

  // decoder
  cvt(z, zb, (long)NROW * DMODEL);
  cvt(decw, dwb, (long)VOCAB * DMODEL);
  k_addbias<<<(VOCAB + 255) / 256, 256, 0, stream>>>(decb, obias, biasD, VOCAB);
  gemm(zb, dwb, out, nullptr, biasD, nullptr, NROW, VOCAB, DMODEL,
       DMODEL, DMODEL, VOCAB, 1, 0, 0, 0, 1.0f);
  k_logsoftmax<<<NROW, 320, 0, stream>>>(out);
}

// Round 3
// 2478.680 us; speedup vs baseline: 1.1742x; 1.1437x over previous
//
#include <hip/hip_runtime.h>

// ---------------- types / constants ----------------
typedef short short8 __attribute__((ext_vector_type(8)));
typedef float f32x4 __attribute__((ext_vector_type(4)));

#define DMODEL 1024
#define HKDIM 1024
#define MDIM 4096
#define NROW 4096   // S*B = 1024*4
#define VOCAB 32000
#define NLAYER 6

#define GLOAD_LDS16(g, l)                                                      \
  __builtin_amdgcn_global_load_lds(                                            \
      (const __attribute__((address_space(1))) void*)(g),                      \
      (__attribute__((address_space(3))) void*)(l), 16, 0, 0)

#define BARRIER_RAW()                      \
  do {                                     \
    __builtin_amdgcn_s_barrier();          \
    __builtin_amdgcn_sched_barrier(0);     \
  } while (0)
#define LGKM0()                                         \
  do {                                                  \
    asm volatile("s_waitcnt lgkmcnt(0)" ::: "memory");  \
    __builtin_amdgcn_sched_barrier(0);                  \
  } while (0)

__device__ __forceinline__ unsigned short f2bf(float f) {
  unsigned u = __float_as_uint(f);
  u += 0x7fffu + ((u >> 16) & 1u);
  return (unsigned short)(u >> 16);
}
__device__ __forceinline__ float bf2f(unsigned short h) {
  return __uint_as_float(((unsigned)h) << 16);
}
__device__ __forceinline__ float wave_sum(float v) {
  for (int o = 32; o; o >>= 1) v += __shfl_xor(v, o);
  return v;
}
__device__ __forceinline__ float wave_max(float v) {
  for (int o = 32; o; o >>= 1) v = fmaxf(v, __shfl_xor(v, o));
  return v;
}

// ---------------- embedding ----------------
__global__ __launch_bounds__(256) void k_embed(const int* __restrict__ x,
    const float* __restrict__ wemb, const float* __restrict__ pemb,
    float* __restrict__ z) {
  int r = blockIdx.x;           // r = s*4 + b
  int s = r >> 2;
  int tok = x[r];
  float4 a = ((const float4*)(wemb + (long)tok * DMODEL))[threadIdx.x];
  float4 p = ((const float4*)(pemb + (long)s * DMODEL))[threadIdx.x];
  float4 o;
  o.x = fmaxf(a.x * 32.0f + p.x, 0.0f);
  o.y = fmaxf(a.y * 32.0f + p.y, 0.0f);
  o.z = fmaxf(a.z * 32.0f + p.z, 0.0f);
  o.w = fmaxf(a.w * 32.0f + p.w, 0.0f);
  ((float4*)(z + (long)r * DMODEL))[threadIdx.x] = o;
}

// ---------------- permute rows: x = swapaxes(z,0,1) ----------------
__global__ __launch_bounds__(256) void k_permute(const float* __restrict__ zin,
    float* __restrict__ xf, unsigned short* __restrict__ xb, int A0, int A1) {
  int r = blockIdx.x;
  int a1 = r / A0, a0 = r - a1 * A0;
  float4 v = ((const float4*)(zin + (long)(a0 * A1 + a1) * DMODEL))[threadIdx.x];
  ((float4*)(xf + (long)r * DMODEL))[threadIdx.x] = v;
  ushort4 o = make_ushort4(f2bf(v.x), f2bf(v.y), f2bf(v.z), f2bf(v.w));
  ((ushort4*)(xb + (long)r * DMODEL))[threadIdx.x] = o;
}

// ---------------- f32 -> bf16 ----------------
__global__ __launch_bounds__(256) void k_cvt(const float* __restrict__ in,
    unsigned short* __restrict__ out, int n4) {
  int i = blockIdx.x * 256 + threadIdx.x;
  int stride = gridDim.x * 256;
  for (; i < n4; i += stride) {
    float4 v = ((const float4*)in)[i];
    ((ushort4*)out)[i] = make_ushort4(f2bf(v.x), f2bf(v.y), f2bf(v.z), f2bf(v.w));
  }
}

// ---------------- 128x128 bf16 GEMM: gload_lds + T2 source/read swizzle ------------
__global__ __launch_bounds__(256) void k_gemm_bt(
    const unsigned short* __restrict__ A, const unsigned short* __restrict__ B,
    float* __restrict__ Cf, unsigned short* __restrict__ Cb,
    const float* __restrict__ bias, const float* __restrict__ res,
    int M, int N, int K, int lda, int ldb, int ldc,
    long aB, long bB, long cB, float scale) {
  __shared__ unsigned short As[128 * 64];
  __shared__ unsigned short Bs[128 * 64];
  const int tid = threadIdx.x;
  const int gx = gridDim.x, gy = gridDim.y;

  int nwg = gx * gy * gridDim.z;
  int flat = blockIdx.x + gx * (blockIdx.y + gy * blockIdx.z);
  int q8 = nwg >> 3, r8 = nwg & 7;
  int xcd = flat & 7, inner = flat >> 3;
  int wg = (xcd < r8 ? xcd * (q8 + 1) : r8 * (q8 + 1) + (xcd - r8) * q8) + inner;
  int ty = wg % gy;
  int rest = wg / gy;
  int tx = rest % gx;
  int tz = rest / gx;

  const unsigned short* Ab = A + (long)tz * aB;
  const unsigned short* Bb = B + (long)tz * bB;
  const int row0 = ty * 128, col0 = tx * 128;
  const int lane = tid & 63, w = tid >> 6;
  const int wm = w >> 1, wn = w & 1;
  const int fr = lane & 15, fg = lane >> 4, fr7 = fr & 7;
  const int lrow = lane >> 3;
  const int lcol = ((lane & 7) ^ lrow) * 8;  // T2: pre-swizzled global source chunk

  const unsigned short* aSrc = Ab + (long)(row0 + w * 32 + lrow) * lda + lcol;
  const unsigned short* bSrc = Bb + (long)(col0 + w * 32 + lrow) * ldb + lcol;
  unsigned short* aDst = As + w * 32 * 64;  // linear wave-uniform LDS dest
  unsigned short* bDst = Bs + w * 32 * 64;

  f32x4 acc[4][4];
#pragma unroll
  for (int i = 0; i < 4; ++i)
#pragma unroll
    for (int j = 0; j < 4; ++j)
#pragma unroll
      for (int qq = 0; qq < 4; ++qq) acc[i][j][qq] = 0.0f;

  for (int k0 = 0; k0 < K; k0 += 64) {
#pragma unroll
    for (int i = 0; i < 4; ++i) {
      GLOAD_LDS16(aSrc + (long)i * 8 * lda + k0, aDst + i * 512);
      GLOAD_LDS16(bSrc + (long)i * 8 * ldb + k0, bDst + i * 512);
    }
    __syncthreads();
#pragma unroll
    for (int kk = 0; kk < 64; kk += 32) {
      short8 af[4], bfr[4];
#pragma unroll
      for (int i = 0; i < 4; ++i) {
        af[i] = *(const short8*)(As + (wm * 64 + i * 16 + fr) * 64 +
                                 (((kk >> 3) + fg) ^ fr7) * 8);
        bfr[i] = *(const short8*)(Bs + (wn * 64 + i * 16 + fr) * 64 +
                                  (((kk >> 3) + fg) ^ fr7) * 8);
      }
#pragma unroll
      for (int i = 0; i < 4; ++i)
#pragma unroll
        for (int j = 0; j < 4; ++j)
          acc[i][j] = __builtin_amdgcn_mfma_f32_16x16x32_bf16(af[i], bfr[j], acc[i][j], 0, 0, 0);
    }
    __syncthreads();
  }

#pragma unroll
  for (int j = 0; j < 4; ++j) {
    int col = col0 + wn * 64 + j * 16 + fr;
    float bv = bias ? bias[col] : 0.0f;
#pragma unroll
    for (int i = 0; i < 4; ++i) {
#pragma unroll
      for (int qq = 0; qq < 4; ++qq) {
        int row = row0 + wm * 64 + i * 16 + fg * 4 + qq;
        long off = cB * tz + (long)row * ldc + col;
        float v = acc[i][j][qq] * scale + bv;
        if (res) v += res[off];
        if (Cf) Cf[off] = v;
        if (Cb) Cb[off] = f2bf(v);
      }
    }
  }
}

// ---------------- 256x256 8-phase bf16 GEMM (T1+T2+T3+T4+T5) ----------------
// 512 threads = 8 waves (2M x 4N); per-wave C = 128x64 = acc[8][4]. BK=64, double-
// buffered LDS (parity: even K-tile -> buf0, odd -> buf1). Counted vmcnt(4) at
// phases 4/8 only; each half-tile DMA issued >=1 barrier after its region's last
// ds_read completed. K must be a multiple of 128; M,N multiples of 256.
__global__ __launch_bounds__(512, 2) void k_gemm8(
    const unsigned short* __restrict__ A, const unsigned short* __restrict__ B,
    float* __restrict__ Cf, unsigned short* __restrict__ Cb,
    const float* __restrict__ bias, int M, int N, int K,
    int lda, int ldb, int ldc) {
  __shared__ unsigned short As[2][256 * 64];
  __shared__ unsigned short Bs[2][256 * 64];
  const int tid = threadIdx.x;
  const int gx = gridDim.x, gy = gridDim.y;
  int nwg = gx * gy;
  int flat = blockIdx.x + gx * blockIdx.y;
  int q8 = nwg >> 3, r8 = nwg & 7;
  int xcd = flat & 7, inner = flat >> 3;
  int wg = (xcd < r8 ? xcd * (q8 + 1) : r8 * (q8 + 1) + (xcd - r8) * q8) + inner;
  int ty = wg % gy, tx = wg / gy;

  const int row0 = ty * 256, col0 = tx * 256;
  const int lane = tid & 63, w = tid >> 6;
  const int wm = w >> 2, wn = w & 3;
  const int fr = lane & 15, fg = lane >> 4, fr7 = fr & 7;
  const int srow = lane >> 3;                 // 0..7 within an 8-row group
  const int scol = ((lane & 7) ^ srow) * 8;   // T2 pre-swizzled source chunk

  // stage one half-tile (128 rows x 64 cols) = 2 global_load_lds_dwordx4
  auto stage = [&](const unsigned short* __restrict__ mat, int ld, int rbase,
                   int tk, unsigned short* lds, int half) {
    const unsigned short* s =
        mat + (size_t)(rbase + half * 128 + w * 8 + srow) * ld + tk * 64 + scol;
    GLOAD_LDS16(s, lds + (half * 128 + w * 8) * 64);
    GLOAD_LDS16(s + (size_t)64 * ld, lds + (half * 128 + 64 + w * 8) * 64);
  };
  auto rdA = [&](const unsigned short* lds, int i, int kq) -> short8 {
    return *(const short8*)(lds + (wm * 128 + i * 16 + fr) * 64 +
                            (((kq << 2) + fg) ^ fr7) * 8);
  };
  auto rdB = [&](const unsigned short* lds, int j, int kq) -> short8 {
    return *(const short8*)(lds + (wn * 64 + j * 16 + fr) * 64 +
                            (((kq << 2) + fg) ^ fr7) * 8);
  };

  f32x4 acc[8][4];
#pragma unroll
  for (int i = 0; i < 8; ++i)
#pragma unroll
    for (int j = 0; j < 4; ++j)
#pragma unroll
      for (int qq = 0; qq < 4; ++qq) acc[i][j][qq] = 0.0f;

  short8 a8[8], b8[8];

#define RDA4(LDS, I0)                           \
  _Pragma("unroll") for (int i = 0; i < 4; ++i) { \
    a8[i * 2] = rdA(LDS, (I0) + i, 0);          \
    a8[i * 2 + 1] = rdA(LDS, (I0) + i, 1);      \
  }
#define RDB2(LDS, J0)                           \
  _Pragma("unroll") for (int j = 0; j < 2; ++j) { \
    b8[((J0) + j) * 2] = rdB(LDS, (J0) + j, 0); \
    b8[((J0) + j) * 2 + 1] = rdB(LDS, (J0) + j, 1); \
  }
#define MM8(I0, J0)                                                          \
  {                                                                          \
    __builtin_amdgcn_s_setprio(1);                                           \
    _Pragma("unroll") for (int i = 0; i < 4; ++i)                            \
      _Pragma("unroll") for (int j = 0; j < 2; ++j)                          \
        _Pragma("unroll") for (int kq = 0; kq < 2; ++kq)                     \
          acc[(I0) + i][(J0) + j] = __builtin_amdgcn_mfma_f32_16x16x32_bf16( \
              a8[i * 2 + kq], b8[((J0) + j) * 2 + kq],                       \
              acc[(I0) + i][(J0) + j], 0, 0, 0);                             \
    __builtin_amdgcn_s_setprio(0);                                           \
  }

  const int NT = K >> 6;  // K-tiles of 64

  // prologue: tile0 fully, tile1 halves B0,A0  (12 loads); keep 4 in flight
  stage(B, ldb, col0, 0, Bs[0], 0);
  stage(A, lda, row0, 0, As[0], 0);
  stage(A, lda, row0, 0, As[0], 1);
  stage(B, ldb, col0, 0, Bs[0], 1);
  stage(B, ldb, col0, 1, Bs[1], 0);
  stage(A, lda, row0, 1, As[1], 0);
  asm volatile("s_waitcnt vmcnt(4)" ::: "memory");
  BARRIER_RAW();

  for (int t = 0; t < NT; t += 2) {
    const bool more = (t + 2 < NT);
    // ---- P1: quadrant (i0-3, j0-1) of tile t ----
    RDA4(As[0], 0)
    RDB2(Bs[0], 0)
    stage(A, lda, row0, t + 1, As[1], 1);
    BARRIER_RAW(); LGKM0();
    MM8(0, 0)
    BARRIER_RAW();
    // ---- P2: (i0-3, j2-3) ----
    RDB2(Bs[0], 2)
    stage(B, ldb, col0, t + 1, Bs[1], 1);
    BARRIER_RAW(); LGKM0();
    MM8(0, 2)
    BARRIER_RAW();
    // ---- P3: (i4-7, j0-1) ----
    RDA4(As[0], 4)
    if (more) stage(B, ldb, col0, t + 2, Bs[0], 0);
    BARRIER_RAW(); LGKM0();
    MM8(4, 0)
    BARRIER_RAW();
    // ---- P4: (i4-7, j2-3); gate tile t+1 ----
    if (more) {
      stage(A, lda, row0, t + 2, As[0], 0);
      asm volatile("s_waitcnt vmcnt(4)" ::: "memory");
    } else {
      asm volatile("s_waitcnt vmcnt(0)" ::: "memory");
    }
    BARRIER_RAW(); LGKM0();
    MM8(4, 2)
    BARRIER_RAW();
    // ---- P5: quadrant (i0-3, j0-1) of tile t+1 ----
    RDA4(As[1], 0)
    RDB2(Bs[1], 0)
    if (more) stage(A, lda, row0, t + 2, As[0], 1);
    BARRIER_RAW(); LGKM0();
    MM8(0, 0)
    BARRIER_RAW();
    // ---- P6: (i0-3, j2-3) ----
    RDB2(Bs[1], 2)
    if (more) stage(B, ldb, col0, t + 2, Bs[0], 1);
    BARRIER_RAW(); LGKM0();
    MM8(0, 2)
    BARRIER_RAW();
    // ---- P7: (i4-7, j0-1) ----
    RDA4(As[1], 4)
    if (more) stage(B, ldb, col0, t + 3, Bs[1], 0);
    BARRIER_RAW(); LGKM0();
    MM8(4, 0)
    BARRIER_RAW();
    // ---- P8: (i4-7, j2-3); gate tile t+2 ----
    if (more) {
      stage(A, lda, row0, t + 3, As[1], 0);
      asm volatile("s_waitcnt vmcnt(4)" ::: "memory");
    } else {
      asm volatile("s_waitcnt vmcnt(0)" ::: "memory");
    }
    BARRIER_RAW(); LGKM0();
    MM8(4, 2)
    BARRIER_RAW();
  }

  // epilogue: C write
#pragma unroll
  for (int j = 0; j < 4; ++j) {
    int col = col0 + wn * 64 + j * 16 + fr;
    float bv = bias ? bias[col] : 0.0f;
#pragma unroll
    for (int i = 0; i < 8; ++i) {
#pragma unroll
      for (int qq = 0; qq < 4; ++qq) {
        int row = row0 + wm * 128 + i * 16 + fg * 4 + qq;
        size_t off = (size_t)row * ldc + col;
        float v = acc[i][j][qq] + bv;
        if (Cf) Cf[off] = v;
        if (Cb) Cb[off] = f2bf(v);
      }
    }
  }
#undef RDA4
#undef RDB2
#undef MM8
}

// ---------------- layernorm ----------------
__global__ __launch_bounds__(256) void k_ln(const float* __restrict__ X,
    const float* __restrict__ X2, const float* __restrict__ g,
    const float* __restrict__ b, float* __restrict__ outF,
    unsigned short* __restrict__ outB) {
  __shared__ float sm[4];
  int row = blockIdx.x, t = threadIdx.x;
  float4 v = ((const float4*)(X + (long)row * DMODEL))[t];
  if (X2) {
    float4 u = ((const float4*)(X2 + (long)row * DMODEL))[t];
    v.x += u.x; v.y += u.y; v.z += u.z; v.w += u.w;
  }
  float s = wave_sum(v.x + v.y + v.z + v.w);
  if ((t & 63) == 0) sm[t >> 6] = s;
  __syncthreads();
  float mean = (sm[0] + sm[1] + sm[2] + sm[3]) * (1.0f / DMODEL);
  __syncthreads();
  float4 c;
  c.x = v.x - mean; c.y = v.y - mean; c.z = v.z - mean; c.w = v.w - mean;
  float ss = wave_sum(c.x * c.x + c.y * c.y + c.z * c.z + c.w * c.w);
  if ((t & 63) == 0) sm[t >> 6] = ss;
  __syncthreads();
  float var = (sm[0] + sm[1] + sm[2] + sm[3]) * (1.0f / DMODEL);
  float rs = rsqrtf(var + 1e-5f);
  float4 gv = ((const float4*)g)[t], bv = ((const float4*)b)[t];
  float4 o;
  o.x = c.x * rs * gv.x + bv.x;
  o.y = c.y * rs * gv.y + bv.y;
  o.z = c.z * rs * gv.z + bv.z;
  o.w = c.w * rs * gv.w + bv.w;
  if (outF) ((float4*)(outF + (long)row * DMODEL))[t] = o;
  if (outB)
    ((ushort4*)(outB + (long)row * DMODEL))[t] =
        make_ushort4(f2bf(o.x), f2bf(o.y), f2bf(o.z), f2bf(o.w));
}

// ---------------- softmax (rows of 1024) ----------------
__global__ __launch_bounds__(256) void k_softmax(const float* __restrict__ S,
    unsigned short* __restrict__ A) {
  __shared__ float sm[4];
  int row = blockIdx.x, t = threadIdx.x;
  float4 v = ((const float4*)(S + (long)row * 1024))[t];
  float m = wave_max(fmaxf(fmaxf(v.x, v.y), fmaxf(v.z, v.w)));
  if ((t & 63) == 0) sm[t >> 6] = m;
  __syncthreads();
  m = fmaxf(fmaxf(sm[0], sm[1]), fmaxf(sm[2], sm[3]));
  __syncthreads();
  float4 e;
  e.x = __expf(v.x - m); e.y = __expf(v.y - m);
  e.z = __expf(v.z - m); e.w = __expf(v.w - m);
  float s = wave_sum(e.x + e.y + e.z + e.w);
  if ((t & 63) == 0) sm[t >> 6] = s;
  __syncthreads();
  float inv = 1.0f / (sm[0] + sm[1] + sm[2] + sm[3]);
  ((ushort4*)(A + (long)row * 1024))[t] =
      make_ushort4(f2bf(e.x * inv), f2bf(e.y * inv), f2bf(e.z * inv), f2bf(e.w * inv));
}

// ---------------- odd layers: seq-4 attention (QKV packed, stride 3072) -------------
__global__ __launch_bounds__(256) void k_attn4(const unsigned short* __restrict__ QKV,
    unsigned short* __restrict__ C) {
  int bp = blockIdx.x;
  int w = threadIdx.x >> 6, lane = threadIdx.x & 63;
  const unsigned short* q = QKV + (long)(bp * 4 + w) * 3072;
  float s[4];
  for (int j = 0; j < 4; ++j) {
    const unsigned short* kj = QKV + (long)(bp * 4 + j) * 3072 + 1024;
    float a = 0.0f;
    for (int e = lane; e < 1024; e += 64) a += bf2f(q[e]) * bf2f(kj[e]);
    s[j] = wave_sum(a) * (1.0f / 32.0f);
  }
  float m = fmaxf(fmaxf(s[0], s[1]), fmaxf(s[2], s[3]));
  float e0 = __expf(s[0] - m), e1 = __expf(s[1] - m);
  float e2 = __expf(s[2] - m), e3 = __expf(s[3] - m);
  float inv = 1.0f / (e0 + e1 + e2 + e3);
  float a0 = e0 * inv, a1 = e1 * inv, a2 = e2 * inv, a3 = e3 * inv;
  unsigned short* c = C + (long)(bp * 4 + w) * 1024;
  const unsigned short* v0 = QKV + (long)(bp * 4 + 0) * 3072 + 2048;
  const unsigned short* v1 = QKV + (long)(bp * 4 + 1) * 3072 + 2048;
  const unsigned short* v2 = QKV + (long)(bp * 4 + 2) * 3072 + 2048;
  const unsigned short* v3 = QKV + (long)(bp * 4 + 3) * 3072 + 2048;
  for (int e = lane; e < 1024; e += 64) {
    float v = a0 * bf2f(v0[e]) + a1 * bf2f(v1[e]) + a2 * bf2f(v2[e]) + a3 * bf2f(v3[e]);
    c[e] = f2bf(v);
  }
}

// ---------------- bf16 batched transpose with strides ----------------
__global__ __launch_bounds__(256) void k_transpose(const unsigned short* __restrict__ in,
    unsigned short* __restrict__ out, int rows, int cols, int ld_in, int ld_out,
    long inB, long outB) {
  __shared__ unsigned short tile[32][33];
  long ibase = (long)blockIdx.z * inB;
  long obase = (long)blockIdx.z * outB;
  int r0 = blockIdx.y * 32, c0 = blockIdx.x * 32;
  int tx = threadIdx.x, ty = threadIdx.y;
  for (int i = ty; i < 32; i += 8)
    tile[i][tx] = in[ibase + (long)(r0 + i) * ld_in + c0 + tx];
  __syncthreads();
  for (int i = ty; i < 32; i += 8)
    out[obase + (long)(c0 + i) * ld_out + r0 + tx] = tile[tx][i];
}

// ---------------- fused log-softmax over rows of 32000 ----------------
__global__ __launch_bounds__(320) void k_logsoftmax(float* __restrict__ L) {
  __shared__ float sm[5];
  int row = blockIdx.x, t = threadIdx.x;
  float* x = L + (long)row * VOCAB;
  float4 v[25];
  float m = -1e30f;
#pragma unroll
  for (int i = 0; i < 25; ++i) {
    v[i] = ((const float4*)x)[t + i * 320];
    m = fmaxf(m, fmaxf(fmaxf(v[i].x, v[i].y), fmaxf(v[i].z, v[i].w)));
  }
  m = wave_max(m);
  if ((t & 63) == 0) sm[t >> 6] = m;
  __syncthreads();
  m = fmaxf(fmaxf(fmaxf(sm[0], sm[1]), fmaxf(sm[2], sm[3])), sm[4]);
  __syncthreads();
  float s = 0.0f;
#pragma unroll
  for (int i = 0; i < 25; ++i)
    s += __expf(v[i].x - m) + __expf(v[i].y - m) + __expf(v[i].z - m) + __expf(v[i].w - m);
  s = wave_sum(s);
  if ((t & 63) == 0) sm[t >> 6] = s;
  __syncthreads();
  float l = m + __logf(sm[0] + sm[1] + sm[2] + sm[3] + sm[4]);
#pragma unroll
  for (int i = 0; i < 25; ++i) {
    float4 o = v[i];
    o.x -= l; o.y -= l; o.z -= l; o.w -= l;
    ((float4*)x)[t + i * 320] = o;
  }
}

__global__ __launch_bounds__(256) void k_addbias(const float* __restrict__ a,
    const float* __restrict__ b, float* __restrict__ o, int n) {
  int i = blockIdx.x * 256 + threadIdx.x;
  if (i < n) o[i] = a[i] + b[i];
}

// ---------------- host ----------------
extern "C" void kernel_launch(void* const* d_in, const int* in_sizes, int n_in,
                              void* d_out, int out_size, void* d_ws, size_t ws_size,
                              hipStream_t stream) {
  const int* x = (const int*)d_in[0];
  const float* wemb = (const float*)d_in[1];
  const float* pemb = (const float*)d_in[2];
  const float* wq = (const float*)d_in[3];
  const float* wk = (const float*)d_in[4];
  const float* wv = (const float*)d_in[5];
  const float* wc = (const float*)d_in[6];
  const float* ln1g = (const float*)d_in[7];
  const float* ln1b = (const float*)d_in[8];
  const float* w1 = (const float*)d_in[9];
  const float* b1 = (const float*)d_in[10];
  const float* w2 = (const float*)d_in[11];
  const float* b2 = (const float*)d_in[12];
  const float* ln2g = (const float*)d_in[13];
  const float* ln2b = (const float*)d_in[14];
  const float* decw = (const float*)d_in[15];
  const float* decb = (const float*)d_in[16];
  const float* obias = (const float*)d_in[17];
  float* out = (float*)d_out;

  char* ws = (char*)d_ws;
  size_t off = 0;
  auto alloc = [&](size_t bytes) -> char* {
    char* p = ws + off;
    off += (bytes + 255) & ~(size_t)255;
    return p;
  };
  float* z = (float*)alloc((size_t)NROW * DMODEL * 4);
  float* xf = (float*)alloc((size_t)NROW * DMODEL * 4);
  unsigned short* xb = (unsigned short*)alloc((size_t)NROW * DMODEL * 2);
  unsigned short* qkv = (unsigned short*)alloc((size_t)NROW * 3072 * 2);
  unsigned short* vt = (unsigned short*)alloc((size_t)NROW * HKDIM * 2);
  unsigned short* wbuf = (unsigned short*)alloc((size_t)MDIM * DMODEL * 2);
  float* tmp16 = (float*)alloc((size_t)NROW * 1024 * 4);
  unsigned short* am = (unsigned short*)alloc((size_t)NROW * 1024 * 2);
  unsigned short* ctx = (unsigned short*)alloc((size_t)NROW * HKDIM * 2);
  float* h = (float*)alloc((size_t)NROW * DMODEL * 4);
  unsigned short* hb = (unsigned short*)alloc((size_t)NROW * DMODEL * 2);
  unsigned short* f = (unsigned short*)alloc((size_t)NROW * MDIM * 2);
  unsigned short* dwb = (unsigned short*)alloc((size_t)VOCAB * DMODEL * 2);
  unsigned short* zb = (unsigned short*)alloc((size_t)NROW * DMODEL * 2);
  float* biasD = (float*)alloc((size_t)VOCAB * 4);
  (void)ws_size; (void)in_sizes; (void)n_in; (void)out_size;

  auto gemm = [&](const unsigned short* A, const unsigned short* B, float* Cf,
                  unsigned short* Cb, const float* bias, const float* res, int M,
                  int N, int K, int lda, int ldb, int ldc, int batch, long aB,
                  long bB, long cB, float scale) {
    dim3 g(N / 128, M / 128, batch);
    k_gemm_bt<<<g, dim3(256), 0, stream>>>(A, B, Cf, Cb, bias, res, M, N, K,
                                           lda, ldb, ldc, aB, bB, cB, scale);
  };
  auto gemm8 = [&](const unsigned short* A, const unsigned short* B, float* Cf,
                   unsigned short* Cb, const float* bias, int M, int N, int K,
                   int lda, int ldb, int ldc) {
    k_gemm8<<<dim3(N / 256, M / 256, 1), dim3(512), 0, stream>>>(
        A, B, Cf, Cb, bias, M, N, K, lda, ldb, ldc);
  };
  auto cvt = [&](const float* in, unsigned short* o, long n) {
    int n4 = (int)(n / 4);
    int grid = (n4 + 255) / 256;
    if (grid > 2048) grid = 2048;
    k_cvt<<<dim3(grid), dim3(256), 0, stream>>>(in, o, n4);
  };

  k_embed<<<NROW, 256, 0, stream>>>(x, wemb, pemb, z);

  for (int i = 0; i < NLAYER; ++i) {
    int A0 = (i % 2 == 0) ? 1024 : 4;
    int A1 = 4096 / A0;
    k_permute<<<NROW, 256, 0, stream>>>(z, xf, xb, A0, A1);

    // merged QKV: weights stacked [3072,1024]
    cvt(wq + (long)i * HKDIM * DMODEL, wbuf, (long)HKDIM * DMODEL);
    cvt(wk + (long)i * HKDIM * DMODEL, wbuf + (size_t)1024 * DMODEL, (long)HKDIM * DMODEL);
    cvt(wv + (long)i * HKDIM * DMODEL, wbuf + (size_t)2048 * DMODEL, (long)HKDIM * DMODEL);
    gemm8(xb, wbuf, nullptr, qkv, nullptr, NROW, 3072, DMODEL, DMODEL, DMODEL, 3072);

    if (A0 == 1024) {  // even: full attention over S=1024, 4 batches
      gemm(qkv, qkv + 1024, tmp16, nullptr, nullptr, nullptr, 1024, 1024, 1024,
           3072, 3072, 1024, 4, (long)1024 * 3072, (long)1024 * 3072, 1 << 20,
           1.0f / 32.0f);
      k_softmax<<<NROW, 256, 0, stream>>>(tmp16, am);
      k_transpose<<<dim3(32, 32, 4), dim3(32, 8), 0, stream>>>(
          qkv + 2048, vt, 1024, 1024, 3072, 1024, (long)1024 * 3072, 1 << 20);
      gemm(am, vt, nullptr, ctx, nullptr, nullptr, 1024, 1024, 1024,
           1024, 1024, 1024, 4, 1 << 20, 1 << 20, 1 << 20, 1.0f);
    } else {  // odd: seq length 4
      k_attn4<<<1024, 256, 0, stream>>>(qkv, ctx);
    }

    cvt(wc + (long)i * DMODEL * HKDIM, wbuf, (long)DMODEL * HKDIM);
    gemm(ctx, wbuf, tmp16, nullptr, nullptr, xf, NROW, DMODEL, HKDIM,
         HKDIM, HKDIM, DMODEL, 1, 0, 0, 0, 1.0f);
    k_ln<<<NROW, 256, 0, stream>>>(tmp16, nullptr, ln1g + (long)i * DMODEL,
                                   ln1b + (long)i * DMODEL, h, hb);
    cvt(w1 + (long)i * MDIM * DMODEL, wbuf, (long)MDIM * DMODEL);
    gemm8(hb, wbuf, nullptr, f, b1 + (long)i * MDIM, NROW, MDIM, DMODEL,
          DMODEL, DMODEL, MDIM);
    cvt(w2 + (long)i * DMODEL * MDIM, wbuf, (long)DMODEL * MDIM);
    gemm(f, wbuf, tmp16, nullptr, b2 + (long)i * DMODEL, nullptr, NROW, DMODEL, MDIM,
         MDIM, MDIM, DMODEL, 1, 0, 0, 0, 1.0f);
    k_ln<<<NROW, 256, 0, stream>>>(tmp16, h, ln2g + (long)i * DMODEL,
                                   ln2b + (long)i * DMODEL, z, nullptr);
  }

  // decoder
  cvt(z, zb, (long)NROW * DMODEL);
  cvt(decw, dwb, (long)VOCAB * DMODEL);
  k_addbias<<<(VOCAB + 255) / 256, 256, 0, stream>>>(decb, obias, biasD, VOCAB);
  gemm8(zb, dwb, out, nullptr, biasD, NROW, VOCAB, DMODEL, DMODEL, DMODEL, VOCAB);
  k_logsoftmax<<<NROW, 320, 0, stream>>>(out);
}